// Round 3
// baseline (1305.736 us; speedup 1.0000x reference)
//
#include <hip/hip_runtime.h>
#include <stdint.h>

// ws layout (float offsets) — total ~590,720 floats = 2.26 MB
#define WS_QMEAN  0          // [2][64][512] f32 query means (branch0: text, branch1: image)
#define WS_QSCALE 65536      // [2][64]
#define WS_SIM    65664      // [2][64][4096]
#define WS_IDX    589952     // [2][64][4] int
#define WS_SCORE  590464     // [2][64][4] f32

using short8  = __attribute__((ext_vector_type(8))) short;
using floatx4 = __attribute__((ext_vector_type(4))) float;

static __device__ __forceinline__ ushort f2bf(float f){
  union { float f; uint32_t i; } v; v.f = f;
  uint32_t u = v.i;
  return (ushort)((u + 0x7FFFu + ((u >> 16) & 1u)) >> 16);
}
static __device__ __forceinline__ uint32_t pack2(float a, float b){
  return (uint32_t)f2bf(a) | ((uint32_t)f2bf(b) << 16);
}
static __device__ __forceinline__ short8 f8bf(float4 a, float4 b){
  union { short8 s; uint32_t u[4]; } r;
  r.u[0]=pack2(a.x,a.y); r.u[1]=pack2(a.z,a.w);
  r.u[2]=pack2(b.x,b.y); r.u[3]=pack2(b.z,b.w);
  return r.s;
}

// ------------------------------------------------------------- query means (fp32)
// grid 128: id<64 -> text (branch0 query), else image (branch1 query)
__global__ __launch_bounds__(256) void qmean_kernel(
    const float* __restrict__ img, const float* __restrict__ txt,
    float* __restrict__ ws)
{
  int id = blockIdx.x;
  const float* src; float* dst; float* sdst;
  if (id < 64){ src = txt + (size_t)id*16384; dst = ws + WS_QMEAN + id*512;         sdst = ws + WS_QSCALE + id; }
  else { int j=id-64; src = img + (size_t)j*16384; dst = ws + WS_QMEAN + 32768 + j*512; sdst = ws + WS_QSCALE + 64 + j; }
  int t = threadIdx.x;
  int d4 = t & 127, sh = t >> 7;
  const float4* s4 = (const float4*)src;   // 4096 float4: s*128 + d4
  float4 acc = {0.f,0.f,0.f,0.f};
  #pragma unroll 4
  for (int s = sh; s < 32; s += 2){
    float4 v = s4[s*128 + d4];
    acc.x+=v.x; acc.y+=v.y; acc.z+=v.z; acc.w+=v.w;
  }
  __shared__ float4 red[256];
  __shared__ float rs2[128];
  red[t] = acc;
  __syncthreads();
  if (t < 128){
    float4 a = red[t], b = red[t+128];
    float4 m = { (a.x+b.x)*(1.f/32.f), (a.y+b.y)*(1.f/32.f),
                 (a.z+b.z)*(1.f/32.f), (a.w+b.w)*(1.f/32.f) };
    ((float4*)dst)[t] = m;
    rs2[t] = m.x*m.x + m.y*m.y + m.z*m.z + m.w*m.w;
  }
  __syncthreads();
  if (t==0){
    float q=0.f;
    for (int i=0;i<128;i++) q+=rs2[i];
    *sdst = 1.f / fmaxf(sqrtf(q), 1e-8f);
  }
}

// ------------------------------------------------------------- fused mem-mean + sim (fp32)
// grid 512: branch = bid>>8, ntile = bid&255 (16 memory rows per block)
__global__ __launch_bounds__(256) void memsim_kernel(
    const float* __restrict__ mi, const float* __restrict__ mt,
    float* __restrict__ ws)
{
  int branch = blockIdx.x >> 8, ntile = blockIdx.x & 255;
  const float* mem = branch ? mt : mi;
  int t = threadIdx.x;
  __shared__ __align__(16) float lm[16][512];
  __shared__ float sp1[16][16], sp2[16][16];
  __shared__ float sscale[16];
  int r = t >> 4, l = t & 15;
  const float4* src4 = (const float4*)(mem + (size_t)(ntile*16 + r)*16384);
  #pragma unroll 1
  for (int cb=0; cb<8; cb++){
    int d4 = l + cb*16;                  // 0..127
    float4 acc = {0.f,0.f,0.f,0.f};
    #pragma unroll 4
    for (int s=0;s<32;s++){
      float4 v = src4[s*128 + d4];
      acc.x+=v.x; acc.y+=v.y; acc.z+=v.z; acc.w+=v.w;
    }
    float4 m = { acc.x*(1.f/32.f), acc.y*(1.f/32.f), acc.z*(1.f/32.f), acc.w*(1.f/32.f) };
    *(float4*)&lm[r][d4*4] = m;
  }
  __syncthreads();
  {
    float p1=0.f, p2=0.f;
    #pragma unroll 8
    for (int i=0;i<32;i++){ float m = lm[r][l*32+i]; p1+=m; p2+=m*m; }
    sp1[r][l]=p1; sp2[r][l]=p2;
  }
  __syncthreads();
  if (t < 16){
    float a=0.f,q=0.f;
    for (int i=0;i<16;i++){ a+=sp1[t][i]; q+=sp2[t][i]; }
    float sc = 1.f/fmaxf(sqrtf(q), 1e-8f);
    if (a == 0.f) sc = 0.f;   // valid mask: mean-vector sum == 0
    sscale[t]=sc;
  }
  __syncthreads();
  int b = t & 63, rg = t >> 6;      // each thread: 4 rows (rg*4..+3) x 1 batch b
  const float4* q4 = (const float4*)(ws + WS_QMEAN + branch*32768 + (size_t)b*512);
  float qs = ws[WS_QSCALE + branch*64 + b];
  float a0=0.f,a1=0.f,a2=0.f,a3=0.f;
  #pragma unroll 4
  for (int d4=0; d4<128; d4++){
    float4 qv = q4[d4];
    float4 v0 = *(const float4*)&lm[rg*4+0][d4*4];
    float4 v1 = *(const float4*)&lm[rg*4+1][d4*4];
    float4 v2 = *(const float4*)&lm[rg*4+2][d4*4];
    float4 v3 = *(const float4*)&lm[rg*4+3][d4*4];
    a0 += v0.x*qv.x + v0.y*qv.y + v0.z*qv.z + v0.w*qv.w;
    a1 += v1.x*qv.x + v1.y*qv.y + v1.z*qv.z + v1.w*qv.w;
    a2 += v2.x*qv.x + v2.y*qv.y + v2.z*qv.z + v2.w*qv.w;
    a3 += v3.x*qv.x + v3.y*qv.y + v3.z*qv.z + v3.w*qv.w;
  }
  int nb = ntile*16 + rg*4;
  float* simp = ws + WS_SIM + (size_t)branch*262144 + (size_t)b*4096;
  simp[nb+0] = a0*qs*sscale[rg*4+0];
  simp[nb+1] = a1*qs*sscale[rg*4+1];
  simp[nb+2] = a2*qs*sscale[rg*4+2];
  simp[nb+3] = a3*qs*sscale[rg*4+3];
}

// ------------------------------------------------------------- top-4, ties -> lower index
__global__ __launch_bounds__(256) void topk_kernel(float* __restrict__ ws)
{
  int branch = blockIdx.x >> 6, b = blockIdx.x & 63;
  int t = threadIdx.x;
  const float* simrow = ws + WS_SIM + (size_t)branch*262144 + (size_t)b*4096;
  float v16[16];
  #pragma unroll
  for (int i=0;i<16;i++) v16[i] = simrow[t + i*256];
  __shared__ float rv[256]; __shared__ int ri[256]; __shared__ int chosen[4];
  int* idxout = (int*)(ws + WS_IDX) + (branch*64+b)*4;
  for (int round=0; round<4; round++){
    float bv = -1e30f; int bi = 1<<30;
    #pragma unroll
    for (int i=0;i<16;i++){
      int n = t + i*256;
      bool ex = (round>0 && n==chosen[0]) || (round>1 && n==chosen[1]) || (round>2 && n==chosen[2]);
      float v = v16[i];
      if (!ex && (v > bv || (v == bv && n < bi))){ bv=v; bi=n; }
    }
    rv[t]=bv; ri[t]=bi;
    __syncthreads();
    for (int sft=128; sft>0; sft>>=1){
      if (t < sft){
        float v2=rv[t+sft]; int i2=ri[t+sft];
        if (v2 > rv[t] || (v2 == rv[t] && i2 < ri[t])){ rv[t]=v2; ri[t]=i2; }
      }
      __syncthreads();
    }
    if (t==0){ chosen[round]=ri[0]; idxout[round] = min(max(ri[0],0),4095); }
    __syncthreads();
  }
}

// ------------------------------------------------------------- routing score (mean-commute, fp32)
__global__ __launch_bounds__(256) void score_kernel(
  const float* __restrict__ mi, const float* __restrict__ mt,
  const float* __restrict__ i_rem_w, const float* __restrict__ i_rem_b,
  const float* __restrict__ i_ret_w, const float* __restrict__ i_ret_b,
  const float* __restrict__ t_rem_w, const float* __restrict__ t_rem_b,
  const float* __restrict__ t_ret_w, const float* __restrict__ t_ret_b,
  float* __restrict__ ws)
{
  int branch = blockIdx.x >> 6, b = blockIdx.x & 63;
  int t = threadIdx.x;
  const float* mem   = branch ? mt : mi;
  const float* rem_w = branch ? t_rem_w : i_rem_w;
  const float* rem_b = branch ? t_rem_b : i_rem_b;
  const float* ret_w = branch ? t_ret_w : i_ret_w;
  const float* ret_b = branch ? t_ret_b : i_ret_b;
  __shared__ float xv[512];
  __shared__ float mv[4][512];
  __shared__ float4 red4[256];
  __shared__ float rmean[512];
  __shared__ float partk[4][256];
  __shared__ float logits[4];
  const int* idxw = (const int*)(ws + WS_IDX) + (branch*64+b)*4;
  xv[t]     = ws[WS_QMEAN + branch*32768 + b*512 + t];
  xv[t+256] = ws[WS_QMEAN + branch*32768 + b*512 + t + 256];
  int d4 = t & 127, sh = t >> 7;
  // recompute means of the 4 retrieved memory rows
  for (int kk=0;kk<4;kk++){
    int row = min(max(idxw[kk],0),4095);
    const float4* src = (const float4*)(mem + (size_t)row*16384);
    float4 acc = {0.f,0.f,0.f,0.f};
    #pragma unroll 4
    for (int s=sh;s<32;s+=2){
      float4 v = src[s*128 + d4];
      acc.x+=v.x; acc.y+=v.y; acc.z+=v.z; acc.w+=v.w;
    }
    red4[t]=acc;
    __syncthreads();
    if (t < 128){
      float4 a=red4[t], b2=red4[t+128];
      float4 m = { (a.x+b2.x)*(1.f/32.f), (a.y+b2.y)*(1.f/32.f),
                   (a.z+b2.z)*(1.f/32.f), (a.w+b2.w)*(1.f/32.f) };
      *(float4*)&mv[kk][t*4] = m;
    }
    __syncthreads();
  }
  // rmean = xmean @ rem_w^T + rem_b
  #pragma unroll
  for (int h=0; h<2; h++){
    int e = t + h*256;
    float acc = rem_b[e];
    const float4* wr = (const float4*)(rem_w + (size_t)e*512);
    for (int c=0;c<128;c++){
      float4 w4 = wr[c];
      acc += w4.x*xv[c*4] + w4.y*xv[c*4+1] + w4.z*xv[c*4+2] + w4.w*xv[c*4+3];
    }
    rmean[e] = acc;
  }
  __syncthreads();
  // logits_k = rmean . (mv_k @ ret_w^T + ret_b)
  float p4[4] = {0.f,0.f,0.f,0.f};
  #pragma unroll
  for (int h=0; h<2; h++){
    int e = t + h*256;
    float dk[4]={0.f,0.f,0.f,0.f};
    const float4* wr = (const float4*)(ret_w + (size_t)e*512);
    for (int c=0;c<128;c++){
      float4 w4 = wr[c];
      #pragma unroll
      for (int k=0;k<4;k++)
        dk[k] += w4.x*mv[k][c*4] + w4.y*mv[k][c*4+1] + w4.z*mv[k][c*4+2] + w4.w*mv[k][c*4+3];
    }
    float rm = rmean[e]; float rb = ret_b[e];
    #pragma unroll
    for (int k=0;k<4;k++) p4[k] += rm * (dk[k] + rb);
  }
  #pragma unroll
  for (int k=0;k<4;k++) partk[k][t] = p4[k];
  __syncthreads();
  if (t < 4){
    float s = 0.f;
    for (int tt=0;tt<256;tt++) s += partk[t][tt];
    logits[t] = s;
  }
  __syncthreads();
  if (t == 0){
    float mx = fmaxf(fmaxf(logits[0],logits[1]), fmaxf(logits[2],logits[3]));
    float e0=expf(logits[0]-mx), e1=expf(logits[1]-mx), e2=expf(logits[2]-mx), e3=expf(logits[3]-mx);
    float inv = 1.f/(e0+e1+e2+e3);
    float* so = ws + WS_SCORE + (branch*64+b)*4;
    so[0]=e0*inv; so[1]=e1*inv; so[2]=e2*inv; so[3]=e3*inv;
  }
}

// ------------------------------------------------------------- expert MLP (bf16 MFMA) + fused epilogue
// grid 128: branch = (bid&7)>>2, b = (bid&3) + 4*(bid>>3)
__global__ __launch_bounds__(256) void expert_kernel(
  const float* __restrict__ mi, const float* __restrict__ mt,
  const float* __restrict__ image, const float* __restrict__ text,
  const int* __restrict__ m1, const int* __restrict__ m2,
  const float* __restrict__ i_ew1, const float* __restrict__ i_eb1,
  const float* __restrict__ i_ew2, const float* __restrict__ i_eb2,
  const float* __restrict__ t_ew1, const float* __restrict__ t_eb1,
  const float* __restrict__ t_ew2, const float* __restrict__ t_eb2,
  const float* __restrict__ ws, float* __restrict__ out)
{
  int bid = blockIdx.x;
  int branch = (bid & 7) >> 2;
  int b = (bid & 3) + 4*(bid >> 3);
  int t = threadIdx.x;
  const float* mem = branch ? mt : mi;
  const float* ew1 = branch ? t_ew1 : i_ew1;
  const float* eb1 = branch ? t_eb1 : i_eb1;
  const float* ew2 = branch ? t_ew2 : i_ew2;
  const float* eb2 = branch ? t_eb2 : i_eb2;
  bool m1e = (m1[b]==1), m2e = (m2[b]==1);
  const int*   idxp = (const int*)(ws + WS_IDX) + (branch*64+b)*4;
  const float* scp  = ws + WS_SCORE + (branch*64+b)*4;

  __shared__ __align__(16) ushort lA[32*512];
  __shared__ __align__(16) ushort lH[32*512];

  int lane = t & 63, wv = t >> 6;
  int col = lane & 15, quad = lane >> 4;

  floatx4 wacc0[8], wacc1[8];
  #pragma unroll
  for (int j=0;j<8;j++){ wacc0[j] = (floatx4){0.f,0.f,0.f,0.f}; wacc1[j] = (floatx4){0.f,0.f,0.f,0.f}; }

  #pragma unroll 1
  for (int k=0;k<4;k++){
    int row = min(max(idxp[k],0),4095);
    float sc = scp[k];
    const float* w1 = ew1 + (size_t)k*262144;
    const float* w2 = ew2 + (size_t)k*262144;
    const float* b1 = eb1 + k*512;
    const float* b2 = eb2 + k*512;
    // stage retrieved row (32x512 fp32 -> bf16), XOR-swizzled 16B chunks: chunk c of row s at c^(s&7)
    const float4* srcf = (const float4*)(mem + (size_t)row*16384);
    #pragma unroll
    for (int i=0;i<8;i++){
      int f = t + 256*i;                 // 2048 chunks of 8 bf16
      int s = f >> 6, c = f & 63;
      float4 v0 = srcf[2*f], v1 = srcf[2*f+1];
      uint4 packed;
      packed.x = pack2(v0.x, v0.y); packed.y = pack2(v0.z, v0.w);
      packed.z = pack2(v1.x, v1.y); packed.w = pack2(v1.z, v1.w);
      ((uint4*)lA)[s*64 + (c ^ (s & 7))] = packed;
    }
    __syncthreads();
    // mm1: h[m][e] for wave's e-range (128 cols)
    #pragma unroll 1
    for (int j=0;j<8;j++){
      int e = (wv*8+j)*16 + col;
      floatx4 acc0={0.f,0.f,0.f,0.f}, acc1={0.f,0.f,0.f,0.f};
      const float4* wrow = (const float4*)(w1 + (size_t)e*512);
      #pragma unroll
      for (int kt=0;kt<16;kt++){
        int c0 = kt*4 + quad;
        short8 bf = f8bf(wrow[c0*2], wrow[c0*2+1]);
        short8 a0 = ((const short8*)lA)[col*64      + (c0 ^ (col & 7))];
        short8 a1 = ((const short8*)lA)[(16+col)*64 + (c0 ^ (col & 7))];
        acc0 = __builtin_amdgcn_mfma_f32_16x16x32_bf16(a0, bf, acc0, 0, 0, 0);
        acc1 = __builtin_amdgcn_mfma_f32_16x16x32_bf16(a1, bf, acc1, 0, 0, 0);
      }
      float bias = b1[e];
      int ec = e >> 3, eo = e & 7;
      #pragma unroll
      for (int rr=0;rr<4;rr++){
        int m0 = quad*4 + rr;
        lH[m0*512      + ((ec ^ (m0 & 7))<<3) + eo] = f2bf(fmaxf(acc0[rr] + bias, 0.f));
        lH[(16+m0)*512 + ((ec ^ (m0 & 7))<<3) + eo] = f2bf(fmaxf(acc1[rr] + bias, 0.f));
      }
    }
    __syncthreads();
    // mm2: out[m][f] partial for wave's f-range; weighted accumulate
    #pragma unroll 1
    for (int j=0;j<8;j++){
      int f = (wv*8+j)*16 + col;
      floatx4 acc0={0.f,0.f,0.f,0.f}, acc1={0.f,0.f,0.f,0.f};
      const float4* wrow = (const float4*)(w2 + (size_t)f*512);
      #pragma unroll
      for (int kt=0;kt<16;kt++){
        int c0 = kt*4 + quad;
        short8 bf = f8bf(wrow[c0*2], wrow[c0*2+1]);
        short8 a0 = ((const short8*)lH)[col*64      + (c0 ^ (col & 7))];
        short8 a1 = ((const short8*)lH)[(16+col)*64 + (c0 ^ (col & 7))];
        acc0 = __builtin_amdgcn_mfma_f32_16x16x32_bf16(a0, bf, acc0, 0, 0, 0);
        acc1 = __builtin_amdgcn_mfma_f32_16x16x32_bf16(a1, bf, acc1, 0, 0, 0);
      }
      float bias = b2[f];
      #pragma unroll
      for (int rr=0;rr<4;rr++){
        wacc0[j][rr] += sc*(acc0[rr] + bias);
        wacc1[j][rr] += sc*(acc1[rr] + bias);
      }
    }
    __syncthreads();
  }
  // fused epilogue: write completed_* and gen_*_full regions (fp32 out)
  const float* pass = branch ? text : image;
  size_t rComp = branch ? 1048576u : 0u;        // completed_text : completed_image
  size_t rGen  = branch ? 3145728u : 2097152u;  // gen_text_full : gen_image_full
  bool genmask  = branch ? m1e : m2e;
  bool compmask = branch ? (!m2e && m1e) : (!m1e && m2e);
  #pragma unroll 1
  for (int j=0;j<8;j++){
    int d = (wv*8+j)*16 + col;
    #pragma unroll
    for (int rr=0;rr<4;rr++){
      int s0 = quad*4 + rr;
      {
        size_t eidx = (size_t)b*16384 + (size_t)s0*512 + d;
        float g = wacc0[j][rr];
        out[rGen + eidx]  = genmask  ? g : 0.f;
        out[rComp + eidx] = compmask ? g : pass[eidx];
      }
      {
        size_t eidx = (size_t)b*16384 + (size_t)(16+s0)*512 + d;
        float g = wacc1[j][rr];
        out[rGen + eidx]  = genmask  ? g : 0.f;
        out[rComp + eidx] = compmask ? g : pass[eidx];
      }
    }
  }
}

extern "C" void kernel_launch(void* const* d_in, const int* in_sizes, int n_in,
                              void* d_out, int out_size, void* d_ws, size_t ws_size,
                              hipStream_t stream) {
  (void)in_sizes; (void)n_in; (void)out_size; (void)ws_size;
  const float* image     = (const float*)d_in[0];
  const float* text      = (const float*)d_in[1];
  const int*   m1        = (const int*)d_in[2];
  const int*   m2        = (const int*)d_in[3];
  const float* mem_image = (const float*)d_in[4];
  const float* mem_text  = (const float*)d_in[5];
  const float* i_rem_w = (const float*)d_in[6];
  const float* i_rem_b = (const float*)d_in[7];
  const float* i_ret_w = (const float*)d_in[8];
  const float* i_ret_b = (const float*)d_in[9];
  const float* i_ew1   = (const float*)d_in[10];
  const float* i_eb1   = (const float*)d_in[11];
  const float* i_ew2   = (const float*)d_in[12];
  const float* i_eb2   = (const float*)d_in[13];
  const float* t_rem_w = (const float*)d_in[14];
  const float* t_rem_b = (const float*)d_in[15];
  const float* t_ret_w = (const float*)d_in[16];
  const float* t_ret_b = (const float*)d_in[17];
  const float* t_ew1   = (const float*)d_in[18];
  const float* t_eb1   = (const float*)d_in[19];
  const float* t_ew2   = (const float*)d_in[20];
  const float* t_eb2   = (const float*)d_in[21];
  float* ws = (float*)d_ws;

  qmean_kernel <<<dim3(128), dim3(256), 0, stream>>>(image, text, ws);
  memsim_kernel<<<dim3(512), dim3(256), 0, stream>>>(mem_image, mem_text, ws);
  topk_kernel  <<<dim3(128), dim3(256), 0, stream>>>(ws);
  score_kernel <<<dim3(128), dim3(256), 0, stream>>>(mem_image, mem_text,
                                                     i_rem_w, i_rem_b, i_ret_w, i_ret_b,
                                                     t_rem_w, t_rem_b, t_ret_w, t_ret_b, ws);
  expert_kernel<<<dim3(128), dim3(256), 0, stream>>>(mem_image, mem_text, image, text, m1, m2,
                                                     i_ew1, i_eb1, i_ew2, i_eb2,
                                                     t_ew1, t_eb1, t_ew2, t_eb2,
                                                     ws, (float*)d_out);
}